// Round 4
// baseline (833.925 us; speedup 1.0000x reference)
//
#include <hip/hip_runtime.h>
#include <hip/hip_bf16.h>

#define LTOT 4096
#define DM 256
#define BATCH 8
#define MROWS (BATCH * LTOT)     // 32768
#define NX ((size_t)MROWS * DM)  // 8388608 elements

typedef __bf16 bf16x8 __attribute__((ext_vector_type(8)));
typedef float f32x4 __attribute__((ext_vector_type(4)));

__device__ __forceinline__ float elu1(float x) {
    return x > 0.f ? x + 1.f : expf(x);
}
__device__ __forceinline__ ushort f2bf(float f) {
    unsigned u = __float_as_uint(f);
    u += 0x7FFFu + ((u >> 16) & 1u);
    return (ushort)(u >> 16);
}
// pack two fp32 -> two bf16 in one dword (RTNE)
__device__ __forceinline__ unsigned pkbf(float a, float b) {
    return (unsigned)f2bf(a) | ((unsigned)f2bf(b) << 16);
}
__device__ __forceinline__ float b2f(ushort u) {
    return __uint_as_float(((unsigned)u) << 16);
}

// ---------------------------------------------------------------------------
// prep: X[b,l,c] = feats[b,c,l] + pos(c,l) (fp32); XC left half = bf16(same)
// ---------------------------------------------------------------------------
__global__ __launch_bounds__(256) void prep_kernel(const float* __restrict__ feats,
                                                   float* __restrict__ X,
                                                   ushort* __restrict__ XC) {
    __shared__ float tile[32][33];
    int b = blockIdx.z;
    int l0 = blockIdx.x * 32;
    int c0 = blockIdx.y * 32;
    int tx = threadIdx.x, ty = threadIdx.y;
#pragma unroll
    for (int j = 0; j < 4; ++j) {
        int c = c0 + ty + j * 8;
        tile[ty + j * 8][tx] = feats[((size_t)(b * DM + c)) * LTOT + l0 + tx];
    }
    __syncthreads();
#pragma unroll
    for (int j = 0; j < 4; ++j) {
        int l = l0 + ty + j * 8;
        int c = c0 + tx;
        int i2 = (c >> 2) * 2;
        float dv = expf((float)i2 * -0.07195578415156063f);
        int rem = c & 3;
        int y = l >> 6, xc = l & 63;
        float pos = (rem < 2) ? (float)(xc + 1) : (float)(y + 1);
        float arg = pos * dv;
        float pe = (rem & 1) ? cosf(arg) : sinf(arg);
        float val = tile[tx][ty + j * 8] + pe;
        size_t row = (size_t)(b * LTOT + l);
        X[row * DM + c] = val;
        XC[row * 512 + c] = f2bf(val);
    }
}

__global__ __launch_bounds__(256) void unprep_kernel(const float* __restrict__ X,
                                                     float* __restrict__ out) {
    __shared__ float tile[32][33];
    int b = blockIdx.z;
    int l0 = blockIdx.x * 32;
    int c0 = blockIdx.y * 32;
    int tx = threadIdx.x, ty = threadIdx.y;
#pragma unroll
    for (int j = 0; j < 4; ++j) {
        int l = l0 + ty + j * 8;
        tile[ty + j * 8][tx] = X[((size_t)(b * LTOT + l)) * DM + c0 + tx];
    }
    __syncthreads();
#pragma unroll
    for (int j = 0; j < 4; ++j) {
        int c = c0 + ty + j * 8;
        out[((size_t)(b * DM + c)) * LTOT + l0 + tx] = tile[tx][ty + j * 8];
    }
}

// ---------------------------------------------------------------------------
// weight transpose + bf16 cast: WT[n][k] = bf16(W[k][n]), z = layer
// ---------------------------------------------------------------------------
__global__ __launch_bounds__(256) void wtrans_kernel(const float* __restrict__ W,
                                                     ushort* __restrict__ WT,
                                                     int K, int N,
                                                     size_t in_ls, size_t out_ls) {
    __shared__ float t[32][33];
    const float* Wz = W + (size_t)blockIdx.z * in_ls;
    ushort* WTz = WT + (size_t)blockIdx.z * out_ls;
    int k0 = blockIdx.x * 32, n0 = blockIdx.y * 32;
    int tx = threadIdx.x, ty = threadIdx.y;
#pragma unroll
    for (int j = 0; j < 4; ++j)
        t[ty + j * 8][tx] = Wz[(size_t)(k0 + ty + j * 8) * N + n0 + tx];
    __syncthreads();
#pragma unroll
    for (int j = 0; j < 4; ++j)
        WTz[(size_t)(n0 + ty + j * 8) * K + k0 + tx] = f2bf(t[tx][ty + j * 8]);
}

// ---------------------------------------------------------------------------
// bf16 MFMA GEMM: Cb[M,N] = act(A[M,K] @ Bt[N,K]^T), bf16 out.
// 128x128 tile, BK=32, 4 waves 2x2, 4x4 frags of 16x16x32.
// Operand-swapped mfma => lane holds 4 CONSECUTIVE COLS of one row:
//   row = m0+wm+i*16+(lane&15), cols = n0+wn+j*16+(lane>>4)*4 + r
// ACT: 2 relu, 3 elu+1 for col<512 else identity (QKV).
// ---------------------------------------------------------------------------
template <int ACT>
__global__ __launch_bounds__(256) void gemm_bf16(const ushort* __restrict__ A, int lda,
                                                 const ushort* __restrict__ Bt,
                                                 ushort* __restrict__ Cb,
                                                 int N, int K) {
    __shared__ ushort As[4096];  // [128][32]
    __shared__ ushort Bs[4096];  // [128][32]
    int tid = threadIdx.x;
    int m0 = blockIdx.x * 128, n0 = blockIdx.y * 128;
    int wave = tid >> 6, lane = tid & 63;
    int wm = (wave >> 1) * 64, wn = (wave & 1) * 64;
    int fm = lane & 15, kg = lane >> 4;

    f32x4 acc[4][4] = {};

    for (int k0 = 0; k0 < K; k0 += 32) {
        const ushort* Ag = A + (size_t)m0 * lda + k0;
        const ushort* Bg = Bt + (size_t)n0 * K + k0;
#pragma unroll
        for (int iss = 0; iss < 2; ++iss) {
            int slot = iss * 256 + tid;
            int rr = slot >> 2, cc = (slot & 3) * 8;
            __builtin_amdgcn_global_load_lds(
                (const __attribute__((address_space(1))) void*)(Ag + (size_t)rr * lda + cc),
                (__attribute__((address_space(3))) void*)(As + iss * 2048 + wave * 512),
                16, 0, 0);
            __builtin_amdgcn_global_load_lds(
                (const __attribute__((address_space(1))) void*)(Bg + (size_t)rr * K + cc),
                (__attribute__((address_space(3))) void*)(Bs + iss * 2048 + wave * 512),
                16, 0, 0);
        }
        __syncthreads();
        bf16x8 afr[4], bfr[4];
#pragma unroll
        for (int i = 0; i < 4; ++i)
            afr[i] = *(const bf16x8*)(As + (wm + i * 16 + fm) * 32 + kg * 8);
#pragma unroll
        for (int j = 0; j < 4; ++j)
            bfr[j] = *(const bf16x8*)(Bs + (wn + j * 16 + fm) * 32 + kg * 8);
#pragma unroll
        for (int i = 0; i < 4; ++i)
#pragma unroll
            for (int j = 0; j < 4; ++j)
                acc[i][j] = __builtin_amdgcn_mfma_f32_16x16x32_bf16(bfr[j], afr[i], acc[i][j], 0, 0, 0);
        __syncthreads();
    }

#pragma unroll
    for (int i = 0; i < 4; ++i) {
        size_t rowoff = (size_t)(m0 + wm + i * 16 + fm) * N;
#pragma unroll
        for (int j = 0; j < 4; ++j) {
            int col = n0 + wn + j * 16 + kg * 4;
            float v0 = acc[i][j][0], v1 = acc[i][j][1], v2 = acc[i][j][2], v3 = acc[i][j][3];
            if (ACT == 2) {
                v0 = fmaxf(v0, 0.f); v1 = fmaxf(v1, 0.f);
                v2 = fmaxf(v2, 0.f); v3 = fmaxf(v3, 0.f);
            }
            if (ACT == 3 && col < 512) {
                v0 = elu1(v0); v1 = elu1(v1); v2 = elu1(v2); v3 = elu1(v3);
            }
            uint2 p;
            p.x = pkbf(v0, v1);
            p.y = pkbf(v2, v3);
            *(uint2*)(Cb + rowoff + col) = p;
        }
    }
}

// ---------------------------------------------------------------------------
// Fused GEMM + LayerNorm: T = A[M,K] @ Bt[256,K]^T; per-row LN over 256.
// Tile 128 rows x 256 cols, 512 threads = 8 waves (wr 2 x wc 4). Operand-
// swapped mfma: row = wr*64+i*16+fm, cols = wc*64+j*16+kg*4 + r.
// RES=0 (LN1):  XC[row*512 + 256 + col] = bf16(LN(T))
// RES=1 (LN2):  X[row][col] += LN(T); XC[row*512 + col] = bf16(X)
// ---------------------------------------------------------------------------
template <int RES>
__global__ __launch_bounds__(512) void gemm_ln(const ushort* __restrict__ A, int lda,
                                               const ushort* __restrict__ Bt, int K,
                                               const float* __restrict__ g,
                                               const float* __restrict__ bta,
                                               float* __restrict__ X,
                                               ushort* __restrict__ XC) {
    __shared__ ushort As[4096];   // [128][32]
    __shared__ ushort Bs[8192];   // [256][32]
    __shared__ float red[128 * 8];
    __shared__ float musig[128 * 2];
    int tid = threadIdx.x;
    int m0 = blockIdx.x * 128;
    int wave = tid >> 6, lane = tid & 63;
    int wr = wave >> 2, wc = wave & 3;
    int fm = lane & 15, kg = lane >> 4;

    f32x4 acc[4][4] = {};

    for (int k0 = 0; k0 < K; k0 += 32) {
        const ushort* Ag = A + (size_t)m0 * lda + k0;
        const ushort* Bg = Bt + k0;
        {
            int rr = tid >> 2, cc = (tid & 3) * 8;
            __builtin_amdgcn_global_load_lds(
                (const __attribute__((address_space(1))) void*)(Ag + (size_t)rr * lda + cc),
                (__attribute__((address_space(3))) void*)(As + wave * 512),
                16, 0, 0);
        }
#pragma unroll
        for (int iss = 0; iss < 2; ++iss) {
            int slot = iss * 512 + tid;
            int rr = slot >> 2, cc = (slot & 3) * 8;
            __builtin_amdgcn_global_load_lds(
                (const __attribute__((address_space(1))) void*)(Bg + (size_t)rr * K + cc),
                (__attribute__((address_space(3))) void*)(Bs + iss * 4096 + wave * 512),
                16, 0, 0);
        }
        __syncthreads();
        bf16x8 afr[4], bfr[4];
#pragma unroll
        for (int i = 0; i < 4; ++i)
            afr[i] = *(const bf16x8*)(As + (wr * 64 + i * 16 + fm) * 32 + kg * 8);
#pragma unroll
        for (int j = 0; j < 4; ++j)
            bfr[j] = *(const bf16x8*)(Bs + (wc * 64 + j * 16 + fm) * 32 + kg * 8);
#pragma unroll
        for (int i = 0; i < 4; ++i)
#pragma unroll
            for (int j = 0; j < 4; ++j)
                acc[i][j] = __builtin_amdgcn_mfma_f32_16x16x32_bf16(bfr[j], afr[i], acc[i][j], 0, 0, 0);
        __syncthreads();
    }

    // per-row partial sums: this lane holds 16 values of row (wr*64+i*16+fm)
    // within this wave's 64-col span; reduce in-lane then across kg (xor 16,32).
#pragma unroll
    for (int i = 0; i < 4; ++i) {
        float s = 0.f, q = 0.f;
#pragma unroll
        for (int j = 0; j < 4; ++j)
#pragma unroll
            for (int r = 0; r < 4; ++r) {
                float v = acc[i][j][r];
                s += v;
                q += v * v;
            }
        s += __shfl_xor(s, 16, 64); q += __shfl_xor(q, 16, 64);
        s += __shfl_xor(s, 32, 64); q += __shfl_xor(q, 32, 64);
        if (kg == 0) {
            int row = wr * 64 + i * 16 + fm;
            red[row * 8 + wc] = s;
            red[row * 8 + 4 + wc] = q;
        }
    }
    __syncthreads();
    if (tid < 128) {
        float s = red[tid * 8 + 0] + red[tid * 8 + 1] + red[tid * 8 + 2] + red[tid * 8 + 3];
        float q = red[tid * 8 + 4] + red[tid * 8 + 5] + red[tid * 8 + 6] + red[tid * 8 + 7];
        float mu = s * (1.f / 256.f);
        float var = q * (1.f / 256.f) - mu * mu;
        musig[tid * 2] = mu;
        musig[tid * 2 + 1] = rsqrtf(var + 1e-5f);
    }
    __syncthreads();

#pragma unroll
    for (int i = 0; i < 4; ++i) {
        int rl = wr * 64 + i * 16 + fm;
        float mu = musig[rl * 2], rstd = musig[rl * 2 + 1];
        size_t grow = (size_t)(m0 + rl);
#pragma unroll
        for (int j = 0; j < 4; ++j) {
            int col = wc * 64 + j * 16 + kg * 4;
            float4 gv = *(const float4*)(g + col);
            float4 bv = *(const float4*)(bta + col);
            float v0 = (acc[i][j][0] - mu) * rstd * gv.x + bv.x;
            float v1 = (acc[i][j][1] - mu) * rstd * gv.y + bv.y;
            float v2 = (acc[i][j][2] - mu) * rstd * gv.z + bv.z;
            float v3 = (acc[i][j][3] - mu) * rstd * gv.w + bv.w;
            if (RES) {
                float4 x4 = *(const float4*)(X + grow * 256 + col);
                x4.x += v0; x4.y += v1; x4.z += v2; x4.w += v3;
                *(float4*)(X + grow * 256 + col) = x4;
                uint2 p;
                p.x = pkbf(x4.x, x4.y);
                p.y = pkbf(x4.z, x4.w);
                *(uint2*)(XC + grow * 512 + col) = p;
            } else {
                uint2 p;
                p.x = pkbf(v0, v1);
                p.y = pkbf(v2, v3);
                *(uint2*)(XC + grow * 512 + 256 + col) = p;
            }
        }
    }
}

// ---------------------------------------------------------------------------
// KV partials: KVp[sp][bh][d][v] = sum_{s in part} K[b,s,h,d]*V[b,s,h,v]
//              KSp[sp][bh][d]   = sum_{s in part} K[b,s,h,d]
// K, V bf16 with row stride `str`. No atomics.
// ---------------------------------------------------------------------------
__global__ __launch_bounds__(256) void kv_kernel(const ushort* __restrict__ Kf,
                                                 const ushort* __restrict__ Vf,
                                                 int str,
                                                 float* __restrict__ KVp,
                                                 float* __restrict__ KSp) {
    __shared__ float Ks[64][36];
    __shared__ float Vs[64][36];
    int tid = threadIdx.x;
    int bh = blockIdx.x;
    int sp = blockIdx.y;
    int b = bh >> 3, h = bh & 7;
    int d = tid >> 3, vb = (tid & 7) * 4;
    float acc0 = 0.f, acc1 = 0.f, acc2 = 0.f, acc3 = 0.f;
    float ksacc = 0.f;
    for (int s0 = sp * 512; s0 < sp * 512 + 512; s0 += 64) {
        for (int i = tid; i < 512; i += 256) {
            int r = i >> 3, c = (i & 7) * 4;
            size_t off = ((size_t)(b * LTOT + s0 + r)) * str + h * 32 + c;
            ushort4 k4 = *(const ushort4*)(Kf + off);
            ushort4 v4 = *(const ushort4*)(Vf + off);
            Ks[r][c + 0] = b2f(k4.x); Ks[r][c + 1] = b2f(k4.y);
            Ks[r][c + 2] = b2f(k4.z); Ks[r][c + 3] = b2f(k4.w);
            Vs[r][c + 0] = b2f(v4.x); Vs[r][c + 1] = b2f(v4.y);
            Vs[r][c + 2] = b2f(v4.z); Vs[r][c + 3] = b2f(v4.w);
        }
        __syncthreads();
#pragma unroll 8
        for (int s = 0; s < 64; ++s) {
            float kd = Ks[s][d];
            acc0 += kd * Vs[s][vb + 0];
            acc1 += kd * Vs[s][vb + 1];
            acc2 += kd * Vs[s][vb + 2];
            acc3 += kd * Vs[s][vb + 3];
        }
        if (tid < 32) {
#pragma unroll 8
            for (int s = 0; s < 64; ++s) ksacc += Ks[s][tid];
        }
        __syncthreads();
    }
    float4 o = make_float4(acc0, acc1, acc2, acc3);
    *(float4*)(KVp + ((size_t)(sp * 64 + bh)) * 1024 + d * 32 + vb) = o;
    if (tid < 32) KSp[(sp * 64 + bh) * 32 + tid] = ksacc;
}

// ---------------------------------------------------------------------------
// reduce partials: KV[bh] = sum_sp KVp[sp][bh]; KS likewise
// ---------------------------------------------------------------------------
__global__ __launch_bounds__(256) void kvreduce_kernel(const float* __restrict__ KVp,
                                                       const float* __restrict__ KSp,
                                                       float* __restrict__ KV,
                                                       float* __restrict__ KS) {
    int bh = blockIdx.x;
    int t = threadIdx.x;
    float4 s = make_float4(0.f, 0.f, 0.f, 0.f);
#pragma unroll
    for (int sp = 0; sp < 8; ++sp) {
        float4 v = *(const float4*)(KVp + ((size_t)(sp * 64 + bh)) * 1024 + t * 4);
        s.x += v.x; s.y += v.y; s.z += v.z; s.w += v.w;
    }
    *(float4*)(KV + (size_t)bh * 1024 + t * 4) = s;
    if (t < 32) {
        float ks = 0.f;
#pragma unroll
        for (int sp = 0; sp < 8; ++sp) ks += KSp[(sp * 64 + bh) * 32 + t];
        KS[bh * 32 + t] = ks;
    }
}

// ---------------------------------------------------------------------------
// msg[b,l,h,v] = (sum_d Q*KV) / (sum_d Q*KS + eps); Q bf16 stride qstr
// ---------------------------------------------------------------------------
__global__ __launch_bounds__(256) void msg_kernel(const ushort* __restrict__ Qb, int qstr,
                                                  const float* __restrict__ KV,
                                                  const float* __restrict__ KS,
                                                  ushort* __restrict__ Msgb) {
    __shared__ float KVs[8 * 1032];
    __shared__ float KSs[256];
    int tid = threadIdx.x;
    int b = blockIdx.y;
    int l0 = blockIdx.x * 32;
    for (int i = tid; i < 8192; i += 256) {
        int h = i >> 10, r = i & 1023;
        KVs[h * 1032 + r] = KV[((size_t)(b * 8 + h)) * 1024 + r];
    }
    KSs[tid] = KS[b * 256 + tid];
    __syncthreads();
    int l = l0 + (tid >> 3);
    int h = tid & 7;
    const ushort* qp = Qb + ((size_t)(b * LTOT + l)) * qstr + h * 32;
    float qv[32];
#pragma unroll
    for (int i = 0; i < 8; ++i) {
        ushort4 q4 = *(const ushort4*)(qp + i * 4);
        qv[i * 4 + 0] = b2f(q4.x); qv[i * 4 + 1] = b2f(q4.y);
        qv[i * 4 + 2] = b2f(q4.z); qv[i * 4 + 3] = b2f(q4.w);
    }
    float den = 1e-6f;
#pragma unroll
    for (int d2 = 0; d2 < 32; ++d2) den += qv[d2] * KSs[h * 32 + d2];
    float rz = 1.f / den;
    float acc[32] = {};
#pragma unroll
    for (int d2 = 0; d2 < 32; ++d2) {
        float qd = qv[d2];
        const float* kvp = &KVs[h * 1032 + d2 * 32];
#pragma unroll
        for (int v = 0; v < 32; ++v) acc[v] += qd * kvp[v];
    }
    ushort* op = Msgb + ((size_t)(b * LTOT + l)) * DM + h * 32;
#pragma unroll
    for (int i = 0; i < 4; ++i) {
        uint2 p;
        p.x = pkbf(acc[i * 8 + 0] * rz, acc[i * 8 + 1] * rz);
        p.y = pkbf(acc[i * 8 + 2] * rz, acc[i * 8 + 3] * rz);
        uint2 p2;
        p2.x = pkbf(acc[i * 8 + 4] * rz, acc[i * 8 + 5] * rz);
        p2.y = pkbf(acc[i * 8 + 6] * rz, acc[i * 8 + 7] * rz);
        *(uint2*)(op + i * 8) = p;
        *(uint2*)(op + i * 8 + 4) = p2;
    }
}

// ---------------------------------------------------------------------------
// Orchestration
// ---------------------------------------------------------------------------
extern "C" void kernel_launch(void* const* d_in, const int* in_sizes, int n_in,
                              void* d_out, int out_size, void* d_ws, size_t ws_size,
                              hipStream_t stream) {
    const float* feats = (const float*)d_in[0];
    const float* Wq = (const float*)d_in[1];
    const float* Wk = (const float*)d_in[2];
    const float* Wv = (const float*)d_in[3];
    const float* Wm = (const float*)d_in[4];
    const float* W1 = (const float*)d_in[5];
    const float* W2 = (const float*)d_in[6];
    const float* g1 = (const float*)d_in[7];
    const float* b1 = (const float*)d_in[8];
    const float* g2 = (const float*)d_in[9];
    const float* b2 = (const float*)d_in[10];

    float* ws = (float*)d_ws;
    float* X = ws;                            // fp32 residual [32768][256]
    ushort* XC = (ushort*)(ws + NX);          // bf16 [32768][512]: [x | LN1(msg)]
    ushort* QKVb = (ushort*)(ws + 2 * NX);    // bf16 [32768][768]; aliased by HBb
    ushort* HBb = QKVb;                       // bf16 [32768][512] MLP hidden

    // d_out doubles as scratch until the final unprep (32 MB)
    float* dout = (float*)d_out;
    ushort* msgb = (ushort*)dout;             // bf16 [32768][256] (16 MB)
    ushort* WB = (ushort*)dout + NX;
    ushort* WTqkv = WB;                       // [4][768][256]
    ushort* WTm = WB + 4 * 196608;            // [4][256][256]
    ushort* WT1 = WTm + 4 * 65536;            // [4][512][512]
    ushort* WT2 = WT1 + 4 * 262144;           // [4][256][512]
    float* KVp = dout + (NX + 2621440) / 2;   // [8][64][1024]
    float* KSp = KVp + 524288;                // [8][64][32]
    float* KV = KSp + 16384;                  // [64][1024]
    float* KS = KV + 65536;                   // [64][32]

    dim3 tblk(32, 8);
    // QKV weights concatenated along n: rows [0,256)=Wq, [256,512)=Wk, [512,768)=Wv
    wtrans_kernel<<<dim3(8, 8, 4), tblk, 0, stream>>>(Wq, WTqkv, 256, 256, 65536, 196608);
    wtrans_kernel<<<dim3(8, 8, 4), tblk, 0, stream>>>(Wk, WTqkv + 65536, 256, 256, 65536, 196608);
    wtrans_kernel<<<dim3(8, 8, 4), tblk, 0, stream>>>(Wv, WTqkv + 131072, 256, 256, 65536, 196608);
    wtrans_kernel<<<dim3(8, 8, 4), tblk, 0, stream>>>(Wm, WTm, 256, 256, 65536, 65536);
    wtrans_kernel<<<dim3(16, 16, 4), tblk, 0, stream>>>(W1, WT1, 512, 512, 262144, 262144);
    wtrans_kernel<<<dim3(16, 8, 4), tblk, 0, stream>>>(W2, WT2, 512, 256, 131072, 131072);

    prep_kernel<<<dim3(128, 8, 8), tblk, 0, stream>>>(feats, X, XC);

    for (int layer = 0; layer < 4; ++layer) {
        const ushort* wtqkv = WTqkv + (size_t)layer * 196608;
        const ushort* wtm = WTm + (size_t)layer * 65536;
        const ushort* wt1 = WT1 + (size_t)layer * 262144;
        const ushort* wt2 = WT2 + (size_t)layer * 131072;
        const float* lg1 = g1 + layer * DM;
        const float* lb1 = b1 + layer * DM;
        const float* lg2 = g2 + layer * DM;
        const float* lb2 = b2 + layer * DM;

        // QKV fused: [32768][768] = elu1/elu1/id( XC[:, :256] @ [Wq|Wk|Wv] )
        gemm_bf16<3><<<dim3(256, 6), 256, 0, stream>>>(XC, 512, wtqkv, QKVb, 768, 256);
        kv_kernel<<<dim3(64, 8), 256, 0, stream>>>(QKVb + 256, QKVb + 512, 768, KVp, KSp);
        kvreduce_kernel<<<64, 256, 0, stream>>>(KVp, KSp, KV, KS);
        msg_kernel<<<dim3(128, 8), 256, 0, stream>>>(QKVb, 768, KV, KS, msgb);
        // Wm GEMM + LN1 fused -> XC right half
        gemm_ln<0><<<256, 512, 0, stream>>>(msgb, 256, wtm, 256, lg1, lb1, nullptr, XC);
        // MLP1: relu( XC[:, :512] @ W1 ) -> HBb  (aliases QKVb, which is dead)
        gemm_bf16<2><<<dim3(256, 4), 256, 0, stream>>>(XC, 512, wt1, HBb, 512, 512);
        // MLP2 + LN2 + residual fused -> X, XC left half
        gemm_ln<1><<<256, 512, 0, stream>>>(HBb, 512, wt2, 512, lg2, lb2, X, XC);
    }

    unprep_kernel<<<dim3(128, 8, 8), tblk, 0, stream>>>(X, dout);
}